// Round 6
// baseline (219.446 us; speedup 1.0000x reference)
//
#include <hip/hip_runtime.h>
#include <hip/hip_bf16.h>

#define NN 50000
#define EE 800000
#define INDIM 128
#define HIDC 16
#define NHEAD 8
#define COARSE 196          // ceil(NN/256)
#define EPB 2048            // edges per block in partition pass A
#define CAPR 6144           // fixed region stride per coarse bin (avg cnt ~4082)
#define CAPB 8192           // partB LDS stage capacity (>= CAPR)
#define CVT_BLKS 37         // ceil((256*128/4 + 32*128/4 + 144)/256)
#define AGG0_BLKS 2048      // persistent grid for k_agg0: 8 blocks/CU

typedef __attribute__((ext_vector_type(8))) short bf16x8;
typedef __attribute__((ext_vector_type(4))) float f32x4;
typedef __attribute__((ext_vector_type(2))) float f32x2;

#if defined(__has_builtin)
#if __has_builtin(__builtin_amdgcn_cvt_pk_f32_fp8)
#define HAVE_PK_F32_FP8 1
#endif
#endif

__device__ __forceinline__ float bf2f(unsigned short u) {
    union { float f; unsigned int i; } v; v.i = ((unsigned int)u) << 16; return v.f;
}
__device__ __forceinline__ unsigned short f2bf(float f) {
    union { float f; unsigned int i; } v; v.f = f;
    unsigned int r = v.i + 0x7FFFu + ((v.i >> 16) & 1u);
    return (unsigned short)(r >> 16);
}

// ---------------------------------------------------------------------------
// K_PREP: blocks [0, CVT_BLKS): weight bf16 conversion + BN constants.
//         blocks [CVT_BLKS, ...): partition pass A (R2-proven, EPB=2048).
// ---------------------------------------------------------------------------
__global__ __launch_bounds__(256) void k_prep(
    const float* __restrict__ w0, const float* __restrict__ skip0,
    const float* __restrict__ w1, const float* __restrict__ skip1,
    const float* __restrict__ b0, const float* __restrict__ g0,
    const float* __restrict__ bb0, const float* __restrict__ m0,
    const float* __restrict__ v0,
    const float* __restrict__ b1, const float* __restrict__ g1,
    const float* __restrict__ bb1, const float* __restrict__ m1,
    const float* __restrict__ v1,
    unsigned int* __restrict__ wb2, unsigned int* __restrict__ wb1_2,
    float2* __restrict__ acb0, float2* __restrict__ acb1,
    const int* __restrict__ ei, int* __restrict__ ccur0,
    unsigned int* __restrict__ pairs)
{
    if (blockIdx.x < CVT_BLKS) {
        const long NW = 256 * 128 / 4;           // w0|skip0 float4 blocks
        const long NW1 = 32 * 128 / 4;           // w1|skip1
        long i = (long)blockIdx.x * 256 + threadIdx.x;
        if (i < NW) {
            const float4* src = (i < 128 * 128 / 4) ? ((const float4*)w0 + i)
                                                    : ((const float4*)skip0 + (i - 128 * 128 / 4));
            float4 v = *src;
            wb2[i * 2]     = (unsigned int)f2bf(v.x) | ((unsigned int)f2bf(v.y) << 16);
            wb2[i * 2 + 1] = (unsigned int)f2bf(v.z) | ((unsigned int)f2bf(v.w) << 16);
        } else if (i < NW + NW1) {
            long j = i - NW;
            const float4* src = (j < 16 * 128 / 4) ? ((const float4*)w1 + j)
                                                   : ((const float4*)skip1 + (j - 16 * 128 / 4));
            float4 v = *src;
            wb1_2[j * 2]     = (unsigned int)f2bf(v.x) | ((unsigned int)f2bf(v.y) << 16);
            wb1_2[j * 2 + 1] = (unsigned int)f2bf(v.z) | ((unsigned int)f2bf(v.w) << 16);
        } else if (i < NW + NW1 + 128) {
            int c = (int)(i - NW - NW1);
            float A = g0[c] * rsqrtf(v0[c] + 1e-5f);
            acb0[c] = make_float2(A, (b0[c] - m0[c]) * A + bb0[c]);
        } else if (i < NW + NW1 + 128 + 16) {
            int c = (int)(i - NW - NW1 - 128);
            float A = g1[c] * rsqrtf(v1[c] + 1e-5f);
            acb1[c] = make_float2(A, (b1[c] - m1[c]) * A + bb1[c]);
        }
        return;
    }

    // ---- partition pass A ----
    __shared__ int bcnt[256];
    __shared__ int lofs[256];
    __shared__ int gofs[256];
    __shared__ unsigned int stage[EPB];
    __shared__ int gpos[EPB];
    const int t = threadIdx.x;
    const int e0 = (blockIdx.x - CVT_BLKS) * EPB;

    bcnt[t] = 0;
    __syncthreads();

    int mybin[8], myrank[8];
    unsigned int mypair[8];
    #pragma unroll
    for (int k = 0; k < 8; k++) {
        int e = e0 + k * 256 + t;
        mybin[k] = -1;
        if (e < EE) {
            int s = ei[e], d = ei[EE + e];
            int b = d >> 8;
            myrank[k] = atomicAdd(&bcnt[b], 1);
            mybin[k] = b;
            mypair[k] = ((unsigned)d << 16) | (unsigned)s;
        }
    }
    __syncthreads();

    int v = bcnt[t];
    lofs[t] = v;
    __syncthreads();
    for (int off = 1; off < 256; off <<= 1) {
        int u = (t >= off) ? lofs[t - off] : 0;
        __syncthreads();
        lofs[t] += u;
        __syncthreads();
    }
    if (t < COARSE && v > 0)
        gofs[t] = t * CAPR + atomicAdd(&ccur0[t], v);
    __syncthreads();

    #pragma unroll
    for (int k = 0; k < 8; k++) {
        int b = mybin[k];
        if (b >= 0) {
            int slot = (lofs[b] - bcnt[b]) + myrank[k];
            stage[slot] = mypair[k];
            gpos[slot]  = gofs[b] + myrank[k];
        }
    }
    __syncthreads();

    const int total = lofs[255];
    for (int i = t; i < total; i += 256)
        pairs[gpos[i]] = stage[i];
}

// ---------------------------------------------------------------------------
// K_MID: blocks [0, COARSE): partition pass B (R2-proven full-bin sort).
//        blocks [COARSE, ...): gemm0 (needs only wb from k_prep).
// ---------------------------------------------------------------------------
__global__ __launch_bounds__(256) void k_mid(
    const unsigned int* __restrict__ pairs, const int* __restrict__ ccur0,
    unsigned short* __restrict__ srcidx, int* __restrict__ rowbeg,
    int* __restrict__ deg,
    const float* __restrict__ x, const unsigned short* __restrict__ wb,
    const float* __restrict__ asrc0, const float* __restrict__ adst0,
    unsigned char* __restrict__ h0f, unsigned short* __restrict__ s0b,
    float* __restrict__ a_src0, float* __restrict__ a_dst0)
{
    __shared__ int fcnt[256], fofs[256], fcur[256];
    __shared__ unsigned short stage[CAPB];

    if (blockIdx.x < COARSE) {
        const int b = blockIdx.x, t = threadIdx.x;
        const int beg = b * CAPR;
        int cnt = ccur0[b];
        if (cnt > CAPR) cnt = CAPR;   // safety clamp

        fcnt[t] = 0;
        __syncthreads();
        for (int i = t; i < cnt; i += 256) {
            unsigned int d = pairs[beg + i] >> 16;
            atomicAdd(&fcnt[d & 255], 1);
        }
        __syncthreads();

        int v = fcnt[t];
        fofs[t] = v;
        __syncthreads();
        for (int off = 1; off < 256; off <<= 1) {
            int u = (t >= off) ? fofs[t - off] : 0;
            __syncthreads();
            fofs[t] += u;
            __syncthreads();
        }
        int ex = fofs[t] - v;
        int node = b * 256 + t;
        if (node < NN) { rowbeg[node] = beg + ex; deg[node] = v; }
        fcur[t] = ex;
        __syncthreads();

        for (int i = t; i < cnt; i += 256) {
            unsigned int p = pairs[beg + i];
            unsigned int d = p >> 16;
            int slot = atomicAdd(&fcur[d & 255], 1);
            stage[slot] = (unsigned short)(p & 0xFFFFu);
        }
        __syncthreads();
        for (int i = t; i < cnt; i += 256)
            srcidx[beg + i] = stage[i];
        return;
    }

    // ---- gemm0 ----
    const int bid = blockIdx.x - COARSE;
    const int wave = threadIdx.x >> 6;
    const int lane = threadIdx.x & 63;
    const int lrow = lane & 15;
    const int quad = lane >> 4;
    const int rowbase = bid * 32;

    // A fragments for 2 row-subtiles, from fp32 x, converted in-register
    bf16x8 afrag[2][4];
    #pragma unroll
    for (int sub = 0; sub < 2; sub++) {
        const int row = min(rowbase + sub * 16 + lrow, NN - 1);
        const float* xr = x + (long)row * 128;
        #pragma unroll
        for (int ki = 0; ki < 4; ki++) {
            float4 a = *(const float4*)(xr + ki * 32 + quad * 8);
            float4 b = *(const float4*)(xr + ki * 32 + quad * 8 + 4);
            bf16x8 f;
            f[0] = (short)f2bf(a.x); f[1] = (short)f2bf(a.y);
            f[2] = (short)f2bf(a.z); f[3] = (short)f2bf(a.w);
            f[4] = (short)f2bf(b.x); f[5] = (short)f2bf(b.y);
            f[6] = (short)f2bf(b.z); f[7] = (short)f2bf(b.w);
            afrag[sub][ki] = f;
        }
    }

    #pragma unroll
    for (int t = 0; t < 4; t++) {
        const int jg = wave * 64 + t * 16 + lrow;
        bf16x8 bfrag[4];
        #pragma unroll
        for (int ki = 0; ki < 4; ki++)
            bfrag[ki] = *(const bf16x8*)(wb + (long)jg * 128 + ki * 32 + quad * 8);
        float4 asv = {0.f, 0.f, 0.f, 0.f}, adv = {0.f, 0.f, 0.f, 0.f};
        if (wave < 2) {
            const int cb = wave * 64 + t * 16 + quad * 4;
            asv = *(const float4*)(asrc0 + cb);
            adv = *(const float4*)(adst0 + cb);
        }
        #pragma unroll
        for (int sub = 0; sub < 2; sub++) {
            f32x4 acc = (f32x4){0.f, 0.f, 0.f, 0.f};
            // swapped operands: D^T -> col(lane&15)=node, row(quad*4+r)=channel
            #pragma unroll
            for (int ki = 0; ki < 4; ki++)
                acc = __builtin_amdgcn_mfma_f32_16x16x32_bf16(bfrag[ki], afrag[sub][ki], acc, 0, 0, 0);

            const int node = rowbase + sub * 16 + lrow;
            if (node < NN) {
                if (wave < 2) {
                    const int cb = wave * 64 + t * 16 + quad * 4;
                    unsigned int u = __builtin_amdgcn_cvt_pk_fp8_f32(acc[0], acc[1], 0u, 0);
                    u = __builtin_amdgcn_cvt_pk_fp8_f32(acc[2], acc[3], u, 1);
                    *(unsigned int*)(h0f + (long)node * 128 + cb) = u;
                    float ps = acc[0] * asv.x + acc[1] * asv.y + acc[2] * asv.z + acc[3] * asv.w;
                    float pd = acc[0] * adv.x + acc[1] * adv.y + acc[2] * adv.z + acc[3] * adv.w;
                    ps += __shfl_xor(ps, 16); ps += __shfl_xor(ps, 32);
                    pd += __shfl_xor(pd, 16); pd += __shfl_xor(pd, 32);
                    if (quad == 0) {
                        const int h = wave * 4 + t;
                        a_src0[(long)node * 8 + h] = ps;
                        a_dst0[(long)node * 8 + h] = pd;
                    }
                } else {
                    const int cb = (wave - 2) * 64 + t * 16 + quad * 4;
                    uint2 u;
                    u.x = (unsigned int)f2bf(acc[0]) | ((unsigned int)f2bf(acc[1]) << 16);
                    u.y = (unsigned int)f2bf(acc[2]) | ((unsigned int)f2bf(acc[3]) << 16);
                    *(uint2*)(s0b + (long)node * 128 + cb) = u;
                }
            }
        }
    }
}

// ---------------------------------------------------------------------------
// K3: layer-0 aggregation + FUSED BN0/skip/ELU epilogue -> hab (bf16 h_act).
// R6: SHUFFLE-FREE inner loop. Lane (q = lane>>4, l16 = lane&15) owns 8 fp8
// channels (head hsel = l16>>1) and edge slots {q, 4+q, 8+q, 12+q} of each
// 16-edge batch. It loads srcidx directly (broadcast across 16 lanes),
// gathers a_src0[s*8+hsel] itself and recomputes exp (2 lanes duplicate each
// (edge,head) — VALU was 50% idle). Chain: vmem->vmem, no DS waits. den is
// recovered by shfl_xor(1|16|32) * 0.5 (each edge counted by 2 lanes).
// ---------------------------------------------------------------------------
__global__ __launch_bounds__(256) void k_agg0(
    const int* __restrict__ rowbeg, const int* __restrict__ deg,
    const unsigned short* __restrict__ srcidx,
    const unsigned char* __restrict__ h0f, const float* __restrict__ a_src0,
    const float* __restrict__ a_dst0, const unsigned short* __restrict__ s0b,
    const float2* __restrict__ acb0, unsigned short* __restrict__ hab)
{
    const int wid = (blockIdx.x * 256 + threadIdx.x) >> 6;   // global wave id
    const int nwaves = AGG0_BLKS * 4;
    const int lane = threadIdx.x & 63;
    const int l16 = lane & 15;
    const int c0 = l16 * 8;                               // 8 fp8 channels
    const int hsel = l16 >> 1;                            // head of c0..c0+7
    const int q = lane >> 4;                              // edge sub-slot

    for (int d = wid; d < NN; d += nwaves) {
        const int beg = rowbeg[d], end = beg + deg[d];
        const float adst = a_dst0[d * 8 + hsel];

        float den = 0.f;
        f32x2 acc2[4] = {(f32x2){0.f, 0.f}, (f32x2){0.f, 0.f},
                         (f32x2){0.f, 0.f}, (f32x2){0.f, 0.f}};
        for (int i = beg; i < end; i += 16) {
            int ss[4];
            float ww[4];
            #pragma unroll
            for (int k = 0; k < 4; k++) {
                const int e = i + k * 4 + q;
                const bool v = e < end;
                const int s = v ? (int)srcidx[e] : 0;     // broadcast (16 lanes same addr)
                float a = a_src0[s * 8 + hsel] + adst;
                a = a > 0.f ? a : 0.2f * a;
                ww[k] = v ? __expf(a) : 0.f;
                ss[k] = s;
                den += ww[k];
            }
            #pragma unroll
            for (int k = 0; k < 4; k++) {
                const uint2 u = *(const uint2*)(h0f + ((unsigned)ss[k] << 7) + c0);
                const float w = ww[k];
#ifdef HAVE_PK_F32_FP8
                acc2[0] += w * __builtin_amdgcn_cvt_pk_f32_fp8((int)u.x, false);
                acc2[1] += w * __builtin_amdgcn_cvt_pk_f32_fp8((int)u.x, true);
                acc2[2] += w * __builtin_amdgcn_cvt_pk_f32_fp8((int)u.y, false);
                acc2[3] += w * __builtin_amdgcn_cvt_pk_f32_fp8((int)u.y, true);
#else
                acc2[0][0] += w * __builtin_amdgcn_cvt_f32_fp8(u.x, 0);
                acc2[0][1] += w * __builtin_amdgcn_cvt_f32_fp8(u.x, 1);
                acc2[1][0] += w * __builtin_amdgcn_cvt_f32_fp8(u.x, 2);
                acc2[1][1] += w * __builtin_amdgcn_cvt_f32_fp8(u.x, 3);
                acc2[2][0] += w * __builtin_amdgcn_cvt_f32_fp8(u.y, 0);
                acc2[2][1] += w * __builtin_amdgcn_cvt_f32_fp8(u.y, 1);
                acc2[3][0] += w * __builtin_amdgcn_cvt_f32_fp8(u.y, 2);
                acc2[3][1] += w * __builtin_amdgcn_cvt_f32_fp8(u.y, 3);
#endif
            }
        }
        // den: lanes (q, 2h) and (q, 2h+1) hold identical edge sets for head h
        // -> sum over l16-bit0 and both q bits counts each edge twice.
        den += __shfl_xor(den, 1);
        den += __shfl_xor(den, 16);
        den += __shfl_xor(den, 32);
        den *= 0.5f;
        #pragma unroll
        for (int p = 0; p < 4; p++) {
            acc2[p][0] += __shfl_xor(acc2[p][0], 16);
            acc2[p][0] += __shfl_xor(acc2[p][0], 32);
            acc2[p][1] += __shfl_xor(acc2[p][1], 16);
            acc2[p][1] += __shfl_xor(acc2[p][1], 32);
        }

        // fused BN0 + skip + ELU, 16 lanes x 8 channels
        if (q == 0) {
            const float inv = 1.f / (den + 1e-16f);
            const float4* abf = (const float4*)((const float*)acb0 + 2 * c0);
            const uint4 su = *(const uint4*)(s0b + (long)d * 128 + c0);
            const unsigned int sw[4] = {su.x, su.y, su.z, su.w};
            unsigned int res[4];
            #pragma unroll
            for (int p = 0; p < 4; p++) {
                const float4 ab = abf[p];                 // (A0,B0,A1,B1)
                float x0 = acc2[p][0] * inv * ab.x + ab.y + bf2f((unsigned short)sw[p]);
                float x1 = acc2[p][1] * inv * ab.z + ab.w + bf2f((unsigned short)(sw[p] >> 16));
                x0 = x0 > 0.f ? x0 : __expf(x0) - 1.f;
                x1 = x1 > 0.f ? x1 : __expf(x1) - 1.f;
                res[p] = (unsigned int)f2bf(x0) | ((unsigned int)f2bf(x1) << 16);
            }
            *(uint4*)(hab + (long)d * 128 + c0) = make_uint4(res[0], res[1], res[2], res[3]);
        }
    }
}

// ---------------------------------------------------------------------------
// K4: slim post0: afrag = direct bf16x8 loads of h_act, two 16x16x32 MFMA
// tiles per 16 nodes -> h1b/s1 + a_src1/a_dst1.
// ---------------------------------------------------------------------------
__global__ __launch_bounds__(256) void k_post0(
    const unsigned short* __restrict__ hab,
    const unsigned short* __restrict__ wb1,     // [32][128] bf16: w1 rows, skip1 rows
    const float* __restrict__ asrc1, const float* __restrict__ adst1,
    unsigned short* __restrict__ h1b, float* __restrict__ s1,
    float* __restrict__ a_src1, float* __restrict__ a_dst1)
{
    const int tid = threadIdx.x;
    const int lane = tid & 63, wave = tid >> 6;
    const int lrow = lane & 15, quad = lane >> 4;

    bf16x8 bfrag[2][4];
    #pragma unroll
    for (int t = 0; t < 2; t++)
        #pragma unroll
        for (int ki = 0; ki < 4; ki++)
            bfrag[t][ki] = *(const bf16x8*)(wb1 + (long)(t * 16 + lrow) * 128 + ki * 32 + quad * 8);
    const float avec = asrc1[lrow];
    const float dvec = adst1[lrow];

    const int tile = blockIdx.x * 4 + wave;           // 16 nodes per tile
    if (tile * 16 >= NN) return;
    const int n0 = tile * 16;
    const long arow = (long)(n0 + lrow) * 128;

    bf16x8 afrag[4];
    #pragma unroll
    for (int ki = 0; ki < 4; ki++)
        afrag[ki] = *(const bf16x8*)(hab + arow + ki * 32 + quad * 8);

    f32x4 acc0 = (f32x4){0.f, 0.f, 0.f, 0.f};   // h1 tile
    f32x4 acc1 = (f32x4){0.f, 0.f, 0.f, 0.f};   // s1 tile
    #pragma unroll
    for (int ki = 0; ki < 4; ki++) {
        acc0 = __builtin_amdgcn_mfma_f32_16x16x32_bf16(afrag[ki], bfrag[0][ki], acc0, 0, 0, 0);
        acc1 = __builtin_amdgcn_mfma_f32_16x16x32_bf16(afrag[ki], bfrag[1][ki], acc1, 0, 0, 0);
    }

    // C layout: col = lane&15 (=j), row = quad*4+r (= node - n0)
    #pragma unroll
    for (int r = 0; r < 4; r++) {
        const int node = n0 + quad * 4 + r;
        h1b[(long)node * 16 + lrow] = f2bf(acc0[r]);
        s1[(long)node * 16 + lrow] = acc1[r];
        float ps = acc0[r] * avec;
        float pd = acc0[r] * dvec;
        ps += __shfl_xor(ps, 1); ps += __shfl_xor(ps, 2);
        ps += __shfl_xor(ps, 4); ps += __shfl_xor(ps, 8);
        pd += __shfl_xor(pd, 1); pd += __shfl_xor(pd, 2);
        pd += __shfl_xor(pd, 4); pd += __shfl_xor(pd, 8);
        if (lrow == 0) { a_src1[node] = ps; a_dst1[node] = pd; }
    }
}

// ---------------------------------------------------------------------------
// K5: layer-1 aggregation + BN1 + skip + ELU -> d_out. 8 lanes per dst node.
// R6: SHUFFLE-FREE inner loop (same scheme as k_agg0). Lane (q = gl>>1,
// chalf = gl&1) owns 8 bf16 channels and edge slots {q,4+q,8+q,12+q};
// direct srcidx/a_src1 loads + redundant exp replace 8 DS shuffles/batch.
// den via shfl_xor(1|2|4) * 0.5.
// ---------------------------------------------------------------------------
__global__ __launch_bounds__(256) void k_agg1_final(
    const int* __restrict__ rowbeg, const int* __restrict__ deg,
    const unsigned short* __restrict__ srcidx,
    const unsigned short* __restrict__ h1b, const float* __restrict__ a_src1,
    const float* __restrict__ a_dst1, const float* __restrict__ s1,
    const float2* __restrict__ acb1, float* __restrict__ out)
{
    const int gid = blockIdx.x * 256 + threadIdx.x;
    const int d = gid >> 3;                               // 8 lanes per node
    if (d >= NN) return;
    const int lane = threadIdx.x & 63;
    const int gl = lane & 7;                              // lane within group
    const int c0 = (gl & 1) * 8;                          // 8 bf16 channels
    const int q = gl >> 1;                                // edge sub-slot 0..3
    const int beg = rowbeg[d], end = beg + deg[d];
    const float adst = a_dst1[d];

    float den = 0.f;
    float acc[8] = {0.f, 0.f, 0.f, 0.f, 0.f, 0.f, 0.f, 0.f};
    for (int i = beg; i < end; i += 16) {
        int ss[4];
        float ww[4];
        #pragma unroll
        for (int k = 0; k < 4; k++) {
            const int e = i + k * 4 + q;
            const bool v = e < end;
            const int s = v ? (int)srcidx[e] : 0;
            float a = a_src1[s] + adst;
            a = a > 0.f ? a : 0.2f * a;
            ww[k] = v ? __expf(a) : 0.f;
            ss[k] = s;
            den += ww[k];
        }
        #pragma unroll
        for (int k = 0; k < 4; k++) {
            const uint4 u = *(const uint4*)(h1b + ss[k] * 16 + c0);
            const float w = ww[k];
            acc[0] += w * bf2f((unsigned short)u.x);
            acc[1] += w * bf2f((unsigned short)(u.x >> 16));
            acc[2] += w * bf2f((unsigned short)u.y);
            acc[3] += w * bf2f((unsigned short)(u.y >> 16));
            acc[4] += w * bf2f((unsigned short)u.z);
            acc[5] += w * bf2f((unsigned short)(u.z >> 16));
            acc[6] += w * bf2f((unsigned short)u.w);
            acc[7] += w * bf2f((unsigned short)(u.w >> 16));
        }
    }
    // each edge counted by 2 lanes (chalf 0/1) -> sum over all 8 lanes, halve
    den += __shfl_xor(den, 1);
    den += __shfl_xor(den, 2);
    den += __shfl_xor(den, 4);
    den *= 0.5f;
    #pragma unroll
    for (int p = 0; p < 8; p++) {
        acc[p] += __shfl_xor(acc[p], 2);
        acc[p] += __shfl_xor(acc[p], 4);
    }

    if (q == 0) {                                         // gl in {0,1}
        const float inv = 1.f / (den + 1e-16f);
        const float4* abf = (const float4*)((const float*)acb1 + 2 * c0);
        const float4 sv0 = *(const float4*)(s1 + (long)d * 16 + c0);
        const float4 sv1 = *(const float4*)(s1 + (long)d * 16 + c0 + 4);
        const float svf[8] = {sv0.x, sv0.y, sv0.z, sv0.w, sv1.x, sv1.y, sv1.z, sv1.w};
        float o[8];
        #pragma unroll
        for (int p = 0; p < 4; p++) {
            const float4 ab = abf[p];                     // (A0,B0,A1,B1)
            float v0o = acc[2 * p]     * inv * ab.x + ab.y + svf[2 * p];
            float v1o = acc[2 * p + 1] * inv * ab.z + ab.w + svf[2 * p + 1];
            o[2 * p]     = v0o > 0.f ? v0o : __expf(v0o) - 1.f;
            o[2 * p + 1] = v1o > 0.f ? v1o : __expf(v1o) - 1.f;
        }
        *(float4*)(out + (long)d * 16 + c0)     = make_float4(o[0], o[1], o[2], o[3]);
        *(float4*)(out + (long)d * 16 + c0 + 4) = make_float4(o[4], o[5], o[6], o[7]);
    }
}

extern "C" void kernel_launch(void* const* d_in, const int* in_sizes, int n_in,
                              void* d_out, int out_size, void* d_ws, size_t ws_size,
                              hipStream_t stream)
{
    (void)in_sizes; (void)n_in; (void)out_size; (void)ws_size;
    const float* x     = (const float*)d_in[0];
    const int*   ei    = (const int*)d_in[1];
    const float* w0    = (const float*)d_in[2];
    const float* asrc0 = (const float*)d_in[3];
    const float* adst0 = (const float*)d_in[4];
    const float* b0    = (const float*)d_in[5];
    const float* skip0 = (const float*)d_in[6];
    const float* bn0g  = (const float*)d_in[7];
    const float* bn0b  = (const float*)d_in[8];
    const float* bn0m  = (const float*)d_in[9];
    const float* bn0v  = (const float*)d_in[10];
    const float* w1    = (const float*)d_in[11];
    const float* asrc1 = (const float*)d_in[12];
    const float* adst1 = (const float*)d_in[13];
    const float* b1    = (const float*)d_in[14];
    const float* skip1 = (const float*)d_in[15];
    const float* bn1g  = (const float*)d_in[16];
    const float* bn1b  = (const float*)d_in[17];
    const float* bn1m  = (const float*)d_in[18];
    const float* bn1v  = (const float*)d_in[19];

    // workspace layout
    const long NPAIR = (long)COARSE * CAPR;                         // 1,204,224
    unsigned int* pairs = (unsigned int*)d_ws;                      // NPAIR u32
    unsigned short* wb    = (unsigned short*)(pairs + NPAIR);       // 256*128 bf16
    unsigned short* wb1   = wb + 256 * 128;                         // 32*128
    unsigned short* s0b   = wb1 + 32 * 128;                         // NN*128
    unsigned short* hab   = s0b + (long)NN * 128;                   // NN*128 (bf16 h_act)
    unsigned short* h1b   = hab + (long)NN * 128;                   // NN*16
    unsigned short* srcidx= h1b + (long)NN * 16;                    // NPAIR u16
    unsigned char*  h0f   = (unsigned char*)(srcidx + NPAIR);       // NN*128 fp8
    float* a_src0 = (float*)(h0f + (long)NN * 128);                 // NN*8
    float* a_dst0 = a_src0 + (long)NN * 8;                          // NN*8
    float* s1     = a_dst0 + (long)NN * 8;                          // NN*16
    float* a_src1 = s1 + (long)NN * 16;                             // NN
    float* a_dst1 = a_src1 + NN;                                    // NN
    float2* acb0  = (float2*)(a_dst1 + NN);                         // 128 float2
    float2* acb1  = acb0 + 128;                                     // 16 float2
    int* ccur0  = (int*)(acb1 + 16);                                // COARSE (zeroed)
    int* rowbeg = ccur0 + COARSE;                                   // NN
    int* deg    = rowbeg + NN;                                      // NN

    hipMemsetAsync(ccur0, 0, (size_t)COARSE * 4, stream);

    // dispatch 1: weight cvt + BN consts  ||  partition pass A
    const int PREP_BLKS = CVT_BLKS + (EE + EPB - 1) / EPB;          // 37 + 391
    k_prep<<<PREP_BLKS, 256, 0, stream>>>(
        w0, skip0, w1, skip1,
        b0, bn0g, bn0b, bn0m, bn0v, b1, bn1g, bn1b, bn1m, bn1v,
        (unsigned int*)wb, (unsigned int*)wb1, acb0, acb1,
        ei, ccur0, pairs);

    // dispatch 2: partition pass B  ||  gemm0 (direct fp32 x)
    const int MID_BLKS = COARSE + (NN + 31) / 32;                   // 196 + 1563
    k_mid<<<MID_BLKS, 256, 0, stream>>>(
        pairs, ccur0, srcidx, rowbeg, deg,
        x, wb, asrc0, adst0, h0f, s0b, a_src0, a_dst0);

    // layer 0 aggregation + fused BN/skip/ELU (persistent grid-stride)
    k_agg0<<<AGG0_BLKS, 256, 0, stream>>>(rowbeg, deg, srcidx, h0f,
                                          a_src0, a_dst0, s0b, acb0,
                                          hab);
    k_post0<<<(NN / 16 + 3) / 4, 256, 0, stream>>>(hab, wb1, asrc1, adst1,
                                                   h1b, s1, a_src1, a_dst1);
    // layer 1 + epilogue
    k_agg1_final<<<(NN * 8 + 255) / 256, 256, 0, stream>>>(rowbeg, deg, srcidx, h1b,
                                                           a_src1, a_dst1, s1,
                                                           acb1, (float*)d_out);
}

// Round 7
// 210.402 us; speedup vs baseline: 1.0430x; 1.0430x over previous
//
#include <hip/hip_runtime.h>
#include <hip/hip_bf16.h>

#define NN 50000
#define EE 800000
#define INDIM 128
#define HIDC 16
#define NHEAD 8
#define COARSE 196          // ceil(NN/256)
#define EPB 2048            // edges per block in partition pass A
#define CAPR 6144           // fixed region stride per coarse bin (avg cnt ~4082)
#define CAPB 8192           // partB LDS stage capacity (>= CAPR)
#define CVT_BLKS 37         // ceil((256*128/4 + 32*128/4 + 144)/256)
#define AGG0_BLKS 2048      // persistent grid for k_agg0: 8 blocks/CU

typedef __attribute__((ext_vector_type(8))) short bf16x8;
typedef __attribute__((ext_vector_type(4))) float f32x4;
typedef __attribute__((ext_vector_type(2))) float f32x2;

#if defined(__has_builtin)
#if __has_builtin(__builtin_amdgcn_cvt_pk_f32_fp8)
#define HAVE_PK_F32_FP8 1
#endif
#endif

__device__ __forceinline__ float bf2f(unsigned short u) {
    union { float f; unsigned int i; } v; v.i = ((unsigned int)u) << 16; return v.f;
}
__device__ __forceinline__ unsigned short f2bf(float f) {
    union { float f; unsigned int i; } v; v.f = f;
    unsigned int r = v.i + 0x7FFFu + ((v.i >> 16) & 1u);
    return (unsigned short)(r >> 16);
}

// ---------------------------------------------------------------------------
// K_PREP: blocks [0, CVT_BLKS): weight bf16 conversion + BN constants.
//         blocks [CVT_BLKS, ...): partition pass A (R2-proven, EPB=2048).
// ---------------------------------------------------------------------------
__global__ __launch_bounds__(256) void k_prep(
    const float* __restrict__ w0, const float* __restrict__ skip0,
    const float* __restrict__ w1, const float* __restrict__ skip1,
    const float* __restrict__ b0, const float* __restrict__ g0,
    const float* __restrict__ bb0, const float* __restrict__ m0,
    const float* __restrict__ v0,
    const float* __restrict__ b1, const float* __restrict__ g1,
    const float* __restrict__ bb1, const float* __restrict__ m1,
    const float* __restrict__ v1,
    unsigned int* __restrict__ wb2, unsigned int* __restrict__ wb1_2,
    float2* __restrict__ acb0, float2* __restrict__ acb1,
    const int* __restrict__ ei, int* __restrict__ ccur0,
    unsigned int* __restrict__ pairs)
{
    if (blockIdx.x < CVT_BLKS) {
        const long NW = 256 * 128 / 4;           // w0|skip0 float4 blocks
        const long NW1 = 32 * 128 / 4;           // w1|skip1
        long i = (long)blockIdx.x * 256 + threadIdx.x;
        if (i < NW) {
            const float4* src = (i < 128 * 128 / 4) ? ((const float4*)w0 + i)
                                                    : ((const float4*)skip0 + (i - 128 * 128 / 4));
            float4 v = *src;
            wb2[i * 2]     = (unsigned int)f2bf(v.x) | ((unsigned int)f2bf(v.y) << 16);
            wb2[i * 2 + 1] = (unsigned int)f2bf(v.z) | ((unsigned int)f2bf(v.w) << 16);
        } else if (i < NW + NW1) {
            long j = i - NW;
            const float4* src = (j < 16 * 128 / 4) ? ((const float4*)w1 + j)
                                                   : ((const float4*)skip1 + (j - 16 * 128 / 4));
            float4 v = *src;
            wb1_2[j * 2]     = (unsigned int)f2bf(v.x) | ((unsigned int)f2bf(v.y) << 16);
            wb1_2[j * 2 + 1] = (unsigned int)f2bf(v.z) | ((unsigned int)f2bf(v.w) << 16);
        } else if (i < NW + NW1 + 128) {
            int c = (int)(i - NW - NW1);
            float A = g0[c] * rsqrtf(v0[c] + 1e-5f);
            acb0[c] = make_float2(A, (b0[c] - m0[c]) * A + bb0[c]);
        } else if (i < NW + NW1 + 128 + 16) {
            int c = (int)(i - NW - NW1 - 128);
            float A = g1[c] * rsqrtf(v1[c] + 1e-5f);
            acb1[c] = make_float2(A, (b1[c] - m1[c]) * A + bb1[c]);
        }
        return;
    }

    // ---- partition pass A ----
    __shared__ int bcnt[256];
    __shared__ int lofs[256];
    __shared__ int gofs[256];
    __shared__ unsigned int stage[EPB];
    __shared__ int gpos[EPB];
    const int t = threadIdx.x;
    const int e0 = (blockIdx.x - CVT_BLKS) * EPB;

    bcnt[t] = 0;
    __syncthreads();

    int mybin[8], myrank[8];
    unsigned int mypair[8];
    #pragma unroll
    for (int k = 0; k < 8; k++) {
        int e = e0 + k * 256 + t;
        mybin[k] = -1;
        if (e < EE) {
            int s = ei[e], d = ei[EE + e];
            int b = d >> 8;
            myrank[k] = atomicAdd(&bcnt[b], 1);
            mybin[k] = b;
            mypair[k] = ((unsigned)d << 16) | (unsigned)s;
        }
    }
    __syncthreads();

    int v = bcnt[t];
    lofs[t] = v;
    __syncthreads();
    for (int off = 1; off < 256; off <<= 1) {
        int u = (t >= off) ? lofs[t - off] : 0;
        __syncthreads();
        lofs[t] += u;
        __syncthreads();
    }
    if (t < COARSE && v > 0)
        gofs[t] = t * CAPR + atomicAdd(&ccur0[t], v);
    __syncthreads();

    #pragma unroll
    for (int k = 0; k < 8; k++) {
        int b = mybin[k];
        if (b >= 0) {
            int slot = (lofs[b] - bcnt[b]) + myrank[k];
            stage[slot] = mypair[k];
            gpos[slot]  = gofs[b] + myrank[k];
        }
    }
    __syncthreads();

    const int total = lofs[255];
    for (int i = t; i < total; i += 256)
        pairs[gpos[i]] = stage[i];
}

// ---------------------------------------------------------------------------
// K_MID: blocks [0, COARSE): partition pass B (R2-proven full-bin sort).
//        blocks [COARSE, ...): gemm0 (needs only wb from k_prep).
// ---------------------------------------------------------------------------
__global__ __launch_bounds__(256) void k_mid(
    const unsigned int* __restrict__ pairs, const int* __restrict__ ccur0,
    unsigned short* __restrict__ srcidx, int* __restrict__ rowbeg,
    int* __restrict__ deg,
    const float* __restrict__ x, const unsigned short* __restrict__ wb,
    const float* __restrict__ asrc0, const float* __restrict__ adst0,
    unsigned char* __restrict__ h0f, unsigned short* __restrict__ s0b,
    float* __restrict__ a_src0, float* __restrict__ a_dst0)
{
    __shared__ int fcnt[256], fofs[256], fcur[256];
    __shared__ unsigned short stage[CAPB];

    if (blockIdx.x < COARSE) {
        const int b = blockIdx.x, t = threadIdx.x;
        const int beg = b * CAPR;
        int cnt = ccur0[b];
        if (cnt > CAPR) cnt = CAPR;   // safety clamp

        fcnt[t] = 0;
        __syncthreads();
        for (int i = t; i < cnt; i += 256) {
            unsigned int d = pairs[beg + i] >> 16;
            atomicAdd(&fcnt[d & 255], 1);
        }
        __syncthreads();

        int v = fcnt[t];
        fofs[t] = v;
        __syncthreads();
        for (int off = 1; off < 256; off <<= 1) {
            int u = (t >= off) ? fofs[t - off] : 0;
            __syncthreads();
            fofs[t] += u;
            __syncthreads();
        }
        int ex = fofs[t] - v;
        int node = b * 256 + t;
        if (node < NN) { rowbeg[node] = beg + ex; deg[node] = v; }
        fcur[t] = ex;
        __syncthreads();

        for (int i = t; i < cnt; i += 256) {
            unsigned int p = pairs[beg + i];
            unsigned int d = p >> 16;
            int slot = atomicAdd(&fcur[d & 255], 1);
            stage[slot] = (unsigned short)(p & 0xFFFFu);
        }
        __syncthreads();
        for (int i = t; i < cnt; i += 256)
            srcidx[beg + i] = stage[i];
        return;
    }

    // ---- gemm0 ----
    const int bid = blockIdx.x - COARSE;
    const int wave = threadIdx.x >> 6;
    const int lane = threadIdx.x & 63;
    const int lrow = lane & 15;
    const int quad = lane >> 4;
    const int rowbase = bid * 32;

    // A fragments for 2 row-subtiles, from fp32 x, converted in-register
    bf16x8 afrag[2][4];
    #pragma unroll
    for (int sub = 0; sub < 2; sub++) {
        const int row = min(rowbase + sub * 16 + lrow, NN - 1);
        const float* xr = x + (long)row * 128;
        #pragma unroll
        for (int ki = 0; ki < 4; ki++) {
            float4 a = *(const float4*)(xr + ki * 32 + quad * 8);
            float4 b = *(const float4*)(xr + ki * 32 + quad * 8 + 4);
            bf16x8 f;
            f[0] = (short)f2bf(a.x); f[1] = (short)f2bf(a.y);
            f[2] = (short)f2bf(a.z); f[3] = (short)f2bf(a.w);
            f[4] = (short)f2bf(b.x); f[5] = (short)f2bf(b.y);
            f[6] = (short)f2bf(b.z); f[7] = (short)f2bf(b.w);
            afrag[sub][ki] = f;
        }
    }

    #pragma unroll
    for (int t = 0; t < 4; t++) {
        const int jg = wave * 64 + t * 16 + lrow;
        bf16x8 bfrag[4];
        #pragma unroll
        for (int ki = 0; ki < 4; ki++)
            bfrag[ki] = *(const bf16x8*)(wb + (long)jg * 128 + ki * 32 + quad * 8);
        float4 asv = {0.f, 0.f, 0.f, 0.f}, adv = {0.f, 0.f, 0.f, 0.f};
        if (wave < 2) {
            const int cb = wave * 64 + t * 16 + quad * 4;
            asv = *(const float4*)(asrc0 + cb);
            adv = *(const float4*)(adst0 + cb);
        }
        #pragma unroll
        for (int sub = 0; sub < 2; sub++) {
            f32x4 acc = (f32x4){0.f, 0.f, 0.f, 0.f};
            // swapped operands: D^T -> col(lane&15)=node, row(quad*4+r)=channel
            #pragma unroll
            for (int ki = 0; ki < 4; ki++)
                acc = __builtin_amdgcn_mfma_f32_16x16x32_bf16(bfrag[ki], afrag[sub][ki], acc, 0, 0, 0);

            const int node = rowbase + sub * 16 + lrow;
            if (node < NN) {
                if (wave < 2) {
                    const int cb = wave * 64 + t * 16 + quad * 4;
                    unsigned int u = __builtin_amdgcn_cvt_pk_fp8_f32(acc[0], acc[1], 0u, 0);
                    u = __builtin_amdgcn_cvt_pk_fp8_f32(acc[2], acc[3], u, 1);
                    *(unsigned int*)(h0f + (long)node * 128 + cb) = u;
                    float ps = acc[0] * asv.x + acc[1] * asv.y + acc[2] * asv.z + acc[3] * asv.w;
                    float pd = acc[0] * adv.x + acc[1] * adv.y + acc[2] * adv.z + acc[3] * adv.w;
                    ps += __shfl_xor(ps, 16); ps += __shfl_xor(ps, 32);
                    pd += __shfl_xor(pd, 16); pd += __shfl_xor(pd, 32);
                    if (quad == 0) {
                        const int h = wave * 4 + t;
                        a_src0[(long)node * 8 + h] = ps;
                        a_dst0[(long)node * 8 + h] = pd;
                    }
                } else {
                    const int cb = (wave - 2) * 64 + t * 16 + quad * 4;
                    uint2 u;
                    u.x = (unsigned int)f2bf(acc[0]) | ((unsigned int)f2bf(acc[1]) << 16);
                    u.y = (unsigned int)f2bf(acc[2]) | ((unsigned int)f2bf(acc[3]) << 16);
                    *(uint2*)(s0b + (long)node * 128 + cb) = u;
                }
            }
        }
    }
}

// ---------------------------------------------------------------------------
// K3: layer-0 aggregation + FUSED BN0/skip/ELU -> hab. R7: TWO NODES PER
// WAVE (X=2d, Y=2d+1) in one straight-line predicated loop body — two
// independent load chains give the scheduler ILP to hide gather latency
// (diagnosed: latency-chain bound; VALUBusy<=61%, instr-count changes don't
// move duration). Shuffle structure identical to the proven R5 kernel.
// ---------------------------------------------------------------------------
__global__ __launch_bounds__(256) void k_agg0(
    const int* __restrict__ rowbeg, const int* __restrict__ deg,
    const unsigned short* __restrict__ srcidx,
    const unsigned char* __restrict__ h0f, const float* __restrict__ a_src0,
    const float* __restrict__ a_dst0, const unsigned short* __restrict__ s0b,
    const float2* __restrict__ acb0, unsigned short* __restrict__ hab)
{
    const int wid = (blockIdx.x * 256 + threadIdx.x) >> 6;   // global wave id
    const int nwaves = AGG0_BLKS * 4;
    const int lane = threadIdx.x & 63;
    const int eslot = lane >> 3;                          // phase-1 edge slot
    const int hph1 = lane & 7;                            // phase-1 head
    const int l16 = lane & 15;
    const int c0 = l16 * 8;                               // phase-2: 8 fp8 channels
    const int hsel = l16 >> 1;                            // head of channels c0..c0+7
    const int q = lane >> 4;                              // phase-2 edge sub-slot

    for (int dd = wid; dd < NN / 2; dd += nwaves) {
        const int X = dd * 2, Y = X + 1;
        const int begX = rowbeg[X], endX = begX + deg[X];
        const int begY = rowbeg[Y], endY = begY + deg[Y];
        const float adX = a_dst0[X * 8 + hph1];
        const float adY = a_dst0[Y * 8 + hph1];

        float denX = 0.f, denY = 0.f;
        f32x2 accX[4] = {(f32x2){0.f, 0.f}, (f32x2){0.f, 0.f},
                         (f32x2){0.f, 0.f}, (f32x2){0.f, 0.f}};
        f32x2 accY[4] = {(f32x2){0.f, 0.f}, (f32x2){0.f, 0.f},
                         (f32x2){0.f, 0.f}, (f32x2){0.f, 0.f}};
        const int nb = max(endX - begX, endY - begY);
        for (int off = 0; off < nb; off += 16) {
            // ---- issue both nodes' index loads ----
            const int xA = begX + off + eslot, xB = xA + 8;
            const int yA = begY + off + eslot, yB = yA + 8;
            const bool vXA = xA < endX, vXB = xB < endX;
            const bool vYA = yA < endY, vYB = yB < endY;
            const int sXA = vXA ? (int)srcidx[xA] : 0;
            const int sXB = vXB ? (int)srcidx[xB] : 0;
            const int sYA = vYA ? (int)srcidx[yA] : 0;
            const int sYB = vYB ? (int)srcidx[yB] : 0;
            // ---- both nodes' weight gathers ----
            float aXA = a_src0[sXA * 8 + hph1] + adX;
            float aXB = a_src0[sXB * 8 + hph1] + adX;
            float aYA = a_src0[sYA * 8 + hph1] + adY;
            float aYB = a_src0[sYB * 8 + hph1] + adY;
            aXA = aXA > 0.f ? aXA : 0.2f * aXA;
            aXB = aXB > 0.f ? aXB : 0.2f * aXB;
            aYA = aYA > 0.f ? aYA : 0.2f * aYA;
            aYB = aYB > 0.f ? aYB : 0.2f * aYB;
            const float wXA = vXA ? __expf(aXA) : 0.f;
            const float wXB = vXB ? __expf(aXB) : 0.f;
            const float wYA = vYA ? __expf(aYA) : 0.f;
            const float wYB = vYB ? __expf(aYB) : 0.f;
            denX += wXA + wXB;
            denY += wYA + wYB;
            // ---- channel gathers, interleaved X/Y ----
            #pragma unroll
            for (int kk = 0; kk < 2; kk++) {
                const int k8 = (kk * 4 + q) * 8;          // edge slot * 8
                const float wxa = __shfl(wXA, k8 + hsel);
                const int   sxa = __shfl(sXA, k8);
                const float wxb = __shfl(wXB, k8 + hsel);
                const int   sxb = __shfl(sXB, k8);
                const float wya = __shfl(wYA, k8 + hsel);
                const int   sya = __shfl(sYA, k8);
                const float wyb = __shfl(wYB, k8 + hsel);
                const int   syb = __shfl(sYB, k8);
                const uint2 uxa = *(const uint2*)(h0f + ((unsigned)sxa << 7) + c0);
                const uint2 uxb = *(const uint2*)(h0f + ((unsigned)sxb << 7) + c0);
                const uint2 uya = *(const uint2*)(h0f + ((unsigned)sya << 7) + c0);
                const uint2 uyb = *(const uint2*)(h0f + ((unsigned)syb << 7) + c0);
#ifdef HAVE_PK_F32_FP8
                accX[0] += wxa * __builtin_amdgcn_cvt_pk_f32_fp8((int)uxa.x, false)
                         + wxb * __builtin_amdgcn_cvt_pk_f32_fp8((int)uxb.x, false);
                accX[1] += wxa * __builtin_amdgcn_cvt_pk_f32_fp8((int)uxa.x, true)
                         + wxb * __builtin_amdgcn_cvt_pk_f32_fp8((int)uxb.x, true);
                accX[2] += wxa * __builtin_amdgcn_cvt_pk_f32_fp8((int)uxa.y, false)
                         + wxb * __builtin_amdgcn_cvt_pk_f32_fp8((int)uxb.y, false);
                accX[3] += wxa * __builtin_amdgcn_cvt_pk_f32_fp8((int)uxa.y, true)
                         + wxb * __builtin_amdgcn_cvt_pk_f32_fp8((int)uxb.y, true);
                accY[0] += wya * __builtin_amdgcn_cvt_pk_f32_fp8((int)uya.x, false)
                         + wyb * __builtin_amdgcn_cvt_pk_f32_fp8((int)uyb.x, false);
                accY[1] += wya * __builtin_amdgcn_cvt_pk_f32_fp8((int)uya.x, true)
                         + wyb * __builtin_amdgcn_cvt_pk_f32_fp8((int)uyb.x, true);
                accY[2] += wya * __builtin_amdgcn_cvt_pk_f32_fp8((int)uya.y, false)
                         + wyb * __builtin_amdgcn_cvt_pk_f32_fp8((int)uyb.y, false);
                accY[3] += wya * __builtin_amdgcn_cvt_pk_f32_fp8((int)uya.y, true)
                         + wyb * __builtin_amdgcn_cvt_pk_f32_fp8((int)uyb.y, true);
#else
                accX[0][0] += wxa * __builtin_amdgcn_cvt_f32_fp8(uxa.x, 0)
                            + wxb * __builtin_amdgcn_cvt_f32_fp8(uxb.x, 0);
                accX[0][1] += wxa * __builtin_amdgcn_cvt_f32_fp8(uxa.x, 1)
                            + wxb * __builtin_amdgcn_cvt_f32_fp8(uxb.x, 1);
                accX[1][0] += wxa * __builtin_amdgcn_cvt_f32_fp8(uxa.x, 2)
                            + wxb * __builtin_amdgcn_cvt_f32_fp8(uxb.x, 2);
                accX[1][1] += wxa * __builtin_amdgcn_cvt_f32_fp8(uxa.x, 3)
                            + wxb * __builtin_amdgcn_cvt_f32_fp8(uxb.x, 3);
                accX[2][0] += wxa * __builtin_amdgcn_cvt_f32_fp8(uxa.y, 0)
                            + wxb * __builtin_amdgcn_cvt_f32_fp8(uxb.y, 0);
                accX[2][1] += wxa * __builtin_amdgcn_cvt_f32_fp8(uxa.y, 1)
                            + wxb * __builtin_amdgcn_cvt_f32_fp8(uxb.y, 1);
                accX[3][0] += wxa * __builtin_amdgcn_cvt_f32_fp8(uxa.y, 2)
                            + wxb * __builtin_amdgcn_cvt_f32_fp8(uxb.y, 2);
                accX[3][1] += wxa * __builtin_amdgcn_cvt_f32_fp8(uxa.y, 3)
                            + wxb * __builtin_amdgcn_cvt_f32_fp8(uxb.y, 3);
                accY[0][0] += wya * __builtin_amdgcn_cvt_f32_fp8(uya.x, 0)
                            + wyb * __builtin_amdgcn_cvt_f32_fp8(uyb.x, 0);
                accY[0][1] += wya * __builtin_amdgcn_cvt_f32_fp8(uya.x, 1)
                            + wyb * __builtin_amdgcn_cvt_f32_fp8(uyb.x, 1);
                accY[1][0] += wya * __builtin_amdgcn_cvt_f32_fp8(uya.x, 2)
                            + wyb * __builtin_amdgcn_cvt_f32_fp8(uyb.x, 2);
                accY[1][1] += wya * __builtin_amdgcn_cvt_f32_fp8(uya.x, 3)
                            + wyb * __builtin_amdgcn_cvt_f32_fp8(uyb.x, 3);
                accY[2][0] += wya * __builtin_amdgcn_cvt_f32_fp8(uya.y, 0)
                            + wyb * __builtin_amdgcn_cvt_f32_fp8(uyb.y, 0);
                accY[2][1] += wya * __builtin_amdgcn_cvt_f32_fp8(uya.y, 1)
                            + wyb * __builtin_amdgcn_cvt_f32_fp8(uyb.y, 1);
                accY[3][0] += wya * __builtin_amdgcn_cvt_f32_fp8(uya.y, 2)
                            + wyb * __builtin_amdgcn_cvt_f32_fp8(uyb.y, 2);
                accY[3][1] += wya * __builtin_amdgcn_cvt_f32_fp8(uya.y, 3)
                            + wyb * __builtin_amdgcn_cvt_f32_fp8(uyb.y, 3);
#endif
            }
        }
        denX += __shfl_xor(denX, 8);
        denX += __shfl_xor(denX, 16);
        denX += __shfl_xor(denX, 32);
        denY += __shfl_xor(denY, 8);
        denY += __shfl_xor(denY, 16);
        denY += __shfl_xor(denY, 32);
        const float dhX = __shfl(denX, hsel);
        const float dhY = __shfl(denY, hsel);
        #pragma unroll
        for (int p = 0; p < 4; p++) {
            accX[p][0] += __shfl_xor(accX[p][0], 16);
            accX[p][0] += __shfl_xor(accX[p][0], 32);
            accX[p][1] += __shfl_xor(accX[p][1], 16);
            accX[p][1] += __shfl_xor(accX[p][1], 32);
            accY[p][0] += __shfl_xor(accY[p][0], 16);
            accY[p][0] += __shfl_xor(accY[p][0], 32);
            accY[p][1] += __shfl_xor(accY[p][1], 16);
            accY[p][1] += __shfl_xor(accY[p][1], 32);
        }

        // fused BN0 + skip + ELU, both nodes, 16 lanes x 8 channels
        if (q == 0) {
            const float invX = 1.f / (dhX + 1e-16f);
            const float invY = 1.f / (dhY + 1e-16f);
            const float4* abf = (const float4*)((const float*)acb0 + 2 * c0);
            const uint4 suX = *(const uint4*)(s0b + (long)X * 128 + c0);
            const uint4 suY = *(const uint4*)(s0b + (long)Y * 128 + c0);
            const unsigned int swX[4] = {suX.x, suX.y, suX.z, suX.w};
            const unsigned int swY[4] = {suY.x, suY.y, suY.z, suY.w};
            unsigned int resX[4], resY[4];
            #pragma unroll
            for (int p = 0; p < 4; p++) {
                const float4 ab = abf[p];                 // (A0,B0,A1,B1)
                float x0 = accX[p][0] * invX * ab.x + ab.y + bf2f((unsigned short)swX[p]);
                float x1 = accX[p][1] * invX * ab.z + ab.w + bf2f((unsigned short)(swX[p] >> 16));
                float y0 = accY[p][0] * invY * ab.x + ab.y + bf2f((unsigned short)swY[p]);
                float y1 = accY[p][1] * invY * ab.z + ab.w + bf2f((unsigned short)(swY[p] >> 16));
                x0 = x0 > 0.f ? x0 : __expf(x0) - 1.f;
                x1 = x1 > 0.f ? x1 : __expf(x1) - 1.f;
                y0 = y0 > 0.f ? y0 : __expf(y0) - 1.f;
                y1 = y1 > 0.f ? y1 : __expf(y1) - 1.f;
                resX[p] = (unsigned int)f2bf(x0) | ((unsigned int)f2bf(x1) << 16);
                resY[p] = (unsigned int)f2bf(y0) | ((unsigned int)f2bf(y1) << 16);
            }
            *(uint4*)(hab + (long)X * 128 + c0) = make_uint4(resX[0], resX[1], resX[2], resX[3]);
            *(uint4*)(hab + (long)Y * 128 + c0) = make_uint4(resY[0], resY[1], resY[2], resY[3]);
        }
    }
}

// ---------------------------------------------------------------------------
// K4: slim post0: afrag = direct bf16x8 loads of h_act, two 16x16x32 MFMA
// tiles per 16 nodes -> h1b/s1 + a_src1/a_dst1.
// ---------------------------------------------------------------------------
__global__ __launch_bounds__(256) void k_post0(
    const unsigned short* __restrict__ hab,
    const unsigned short* __restrict__ wb1,     // [32][128] bf16: w1 rows, skip1 rows
    const float* __restrict__ asrc1, const float* __restrict__ adst1,
    unsigned short* __restrict__ h1b, float* __restrict__ s1,
    float* __restrict__ a_src1, float* __restrict__ a_dst1)
{
    const int tid = threadIdx.x;
    const int lane = tid & 63, wave = tid >> 6;
    const int lrow = lane & 15, quad = lane >> 4;

    bf16x8 bfrag[2][4];
    #pragma unroll
    for (int t = 0; t < 2; t++)
        #pragma unroll
        for (int ki = 0; ki < 4; ki++)
            bfrag[t][ki] = *(const bf16x8*)(wb1 + (long)(t * 16 + lrow) * 128 + ki * 32 + quad * 8);
    const float avec = asrc1[lrow];
    const float dvec = adst1[lrow];

    const int tile = blockIdx.x * 4 + wave;           // 16 nodes per tile
    if (tile * 16 >= NN) return;
    const int n0 = tile * 16;
    const long arow = (long)(n0 + lrow) * 128;

    bf16x8 afrag[4];
    #pragma unroll
    for (int ki = 0; ki < 4; ki++)
        afrag[ki] = *(const bf16x8*)(hab + arow + ki * 32 + quad * 8);

    f32x4 acc0 = (f32x4){0.f, 0.f, 0.f, 0.f};   // h1 tile
    f32x4 acc1 = (f32x4){0.f, 0.f, 0.f, 0.f};   // s1 tile
    #pragma unroll
    for (int ki = 0; ki < 4; ki++) {
        acc0 = __builtin_amdgcn_mfma_f32_16x16x32_bf16(afrag[ki], bfrag[0][ki], acc0, 0, 0, 0);
        acc1 = __builtin_amdgcn_mfma_f32_16x16x32_bf16(afrag[ki], bfrag[1][ki], acc1, 0, 0, 0);
    }

    // C layout: col = lane&15 (=j), row = quad*4+r (= node - n0)
    #pragma unroll
    for (int r = 0; r < 4; r++) {
        const int node = n0 + quad * 4 + r;
        h1b[(long)node * 16 + lrow] = f2bf(acc0[r]);
        s1[(long)node * 16 + lrow] = acc1[r];
        float ps = acc0[r] * avec;
        float pd = acc0[r] * dvec;
        ps += __shfl_xor(ps, 1); ps += __shfl_xor(ps, 2);
        ps += __shfl_xor(ps, 4); ps += __shfl_xor(ps, 8);
        pd += __shfl_xor(pd, 1); pd += __shfl_xor(pd, 2);
        pd += __shfl_xor(pd, 4); pd += __shfl_xor(pd, 8);
        if (lrow == 0) { a_src1[node] = ps; a_dst1[node] = pd; }
    }
}

// ---------------------------------------------------------------------------
// K5: layer-1 aggregation + BN1 + skip + ELU -> d_out. R7: TWO NODES PER
// 8-lane group (X=2g, Y=2g+1), same ILP mechanism as k_agg0. Wide-gather
// structure identical to the proven R2 kernel.
// ---------------------------------------------------------------------------
__global__ __launch_bounds__(256) void k_agg1_final(
    const int* __restrict__ rowbeg, const int* __restrict__ deg,
    const unsigned short* __restrict__ srcidx,
    const unsigned short* __restrict__ h1b, const float* __restrict__ a_src1,
    const float* __restrict__ a_dst1, const float* __restrict__ s1,
    const float2* __restrict__ acb1, float* __restrict__ out)
{
    const int g = (blockIdx.x * 256 + threadIdx.x) >> 3;  // 8 lanes per group
    const int X = g * 2, Y = X + 1;                       // two nodes per group
    if (X >= NN) return;
    const int lane = threadIdx.x & 63;
    const int gl = lane & 7;                              // lane within group
    const int gb = lane & ~7;                             // group base lane
    const int c0 = (gl & 1) * 8;                          // 8 bf16 channels
    const int q = gl >> 1;                                // edge sub-slot 0..3
    const int begX = rowbeg[X], endX = begX + deg[X];
    const int begY = rowbeg[Y], endY = begY + deg[Y];
    const float adX = a_dst1[X];
    const float adY = a_dst1[Y];

    float denX = 0.f, denY = 0.f;
    float accX[8] = {0.f, 0.f, 0.f, 0.f, 0.f, 0.f, 0.f, 0.f};
    float accY[8] = {0.f, 0.f, 0.f, 0.f, 0.f, 0.f, 0.f, 0.f};
    const int nb = max(endX - begX, endY - begY);
    for (int off = 0; off < nb; off += 16) {
        const int xA = begX + off + gl, xB = xA + 8;
        const int yA = begY + off + gl, yB = yA + 8;
        const bool vXA = xA < endX, vXB = xB < endX;
        const bool vYA = yA < endY, vYB = yB < endY;
        const int sXA = vXA ? (int)srcidx[xA] : 0;
        const int sXB = vXB ? (int)srcidx[xB] : 0;
        const int sYA = vYA ? (int)srcidx[yA] : 0;
        const int sYB = vYB ? (int)srcidx[yB] : 0;
        float aXA = a_src1[sXA] + adX;
        float aXB = a_src1[sXB] + adX;
        float aYA = a_src1[sYA] + adY;
        float aYB = a_src1[sYB] + adY;
        aXA = aXA > 0.f ? aXA : 0.2f * aXA;
        aXB = aXB > 0.f ? aXB : 0.2f * aXB;
        aYA = aYA > 0.f ? aYA : 0.2f * aYA;
        aYB = aYB > 0.f ? aYB : 0.2f * aYB;
        const float wXA = vXA ? __expf(aXA) : 0.f;
        const float wXB = vXB ? __expf(aXB) : 0.f;
        const float wYA = vYA ? __expf(aYA) : 0.f;
        const float wYB = vYB ? __expf(aYB) : 0.f;
        denX += wXA + wXB;
        denY += wYA + wYB;
        #pragma unroll
        for (int kk = 0; kk < 2; kk++) {
            const int k = kk * 4 + q;                     // edge slot 0..7
            const float wxa = __shfl(wXA, gb | k);
            const int   sxa = __shfl(sXA, gb | k);
            const float wxb = __shfl(wXB, gb | k);
            const int   sxb = __shfl(sXB, gb | k);
            const float wya = __shfl(wYA, gb | k);
            const int   sya = __shfl(sYA, gb | k);
            const float wyb = __shfl(wYB, gb | k);
            const int   syb = __shfl(sYB, gb | k);
            const uint4 uxa = *(const uint4*)(h1b + sxa * 16 + c0);
            const uint4 uxb = *(const uint4*)(h1b + sxb * 16 + c0);
            const uint4 uya = *(const uint4*)(h1b + sya * 16 + c0);
            const uint4 uyb = *(const uint4*)(h1b + syb * 16 + c0);
            const unsigned int ux[8] = {uxa.x, uxa.y, uxa.z, uxa.w, uxb.x, uxb.y, uxb.z, uxb.w};
            const unsigned int uy[8] = {uya.x, uya.y, uya.z, uya.w, uyb.x, uyb.y, uyb.z, uyb.w};
            #pragma unroll
            for (int p = 0; p < 4; p++) {
                accX[2 * p]     += wxa * bf2f((unsigned short)ux[p]);
                accX[2 * p + 1] += wxa * bf2f((unsigned short)(ux[p] >> 16));
                accX[2 * p]     += wxb * bf2f((unsigned short)ux[p + 4]);
                accX[2 * p + 1] += wxb * bf2f((unsigned short)(ux[p + 4] >> 16));
                accY[2 * p]     += wya * bf2f((unsigned short)uy[p]);
                accY[2 * p + 1] += wya * bf2f((unsigned short)(uy[p] >> 16));
                accY[2 * p]     += wyb * bf2f((unsigned short)uy[p + 4]);
                accY[2 * p + 1] += wyb * bf2f((unsigned short)(uy[p + 4] >> 16));
            }
        }
    }
    denX += __shfl_xor(denX, 1);
    denX += __shfl_xor(denX, 2);
    denX += __shfl_xor(denX, 4);
    denY += __shfl_xor(denY, 1);
    denY += __shfl_xor(denY, 2);
    denY += __shfl_xor(denY, 4);
    #pragma unroll
    for (int p = 0; p < 8; p++) {
        accX[p] += __shfl_xor(accX[p], 2);
        accX[p] += __shfl_xor(accX[p], 4);
        accY[p] += __shfl_xor(accY[p], 2);
        accY[p] += __shfl_xor(accY[p], 4);
    }

    if (q == 0) {                                         // gl in {0,1}
        const float invX = 1.f / (denX + 1e-16f);
        const float invY = 1.f / (denY + 1e-16f);
        const float4* abf = (const float4*)((const float*)acb1 + 2 * c0);
        const float4 svX0 = *(const float4*)(s1 + (long)X * 16 + c0);
        const float4 svX1 = *(const float4*)(s1 + (long)X * 16 + c0 + 4);
        const float4 svY0 = *(const float4*)(s1 + (long)Y * 16 + c0);
        const float4 svY1 = *(const float4*)(s1 + (long)Y * 16 + c0 + 4);
        const float sfX[8] = {svX0.x, svX0.y, svX0.z, svX0.w, svX1.x, svX1.y, svX1.z, svX1.w};
        const float sfY[8] = {svY0.x, svY0.y, svY0.z, svY0.w, svY1.x, svY1.y, svY1.z, svY1.w};
        float oX[8], oY[8];
        #pragma unroll
        for (int p = 0; p < 4; p++) {
            const float4 ab = abf[p];                     // (A0,B0,A1,B1)
            float x0 = accX[2 * p]     * invX * ab.x + ab.y + sfX[2 * p];
            float x1 = accX[2 * p + 1] * invX * ab.z + ab.w + sfX[2 * p + 1];
            float y0 = accY[2 * p]     * invY * ab.x + ab.y + sfY[2 * p];
            float y1 = accY[2 * p + 1] * invY * ab.z + ab.w + sfY[2 * p + 1];
            oX[2 * p]     = x0 > 0.f ? x0 : __expf(x0) - 1.f;
            oX[2 * p + 1] = x1 > 0.f ? x1 : __expf(x1) - 1.f;
            oY[2 * p]     = y0 > 0.f ? y0 : __expf(y0) - 1.f;
            oY[2 * p + 1] = y1 > 0.f ? y1 : __expf(y1) - 1.f;
        }
        *(float4*)(out + (long)X * 16 + c0)     = make_float4(oX[0], oX[1], oX[2], oX[3]);
        *(float4*)(out + (long)X * 16 + c0 + 4) = make_float4(oX[4], oX[5], oX[6], oX[7]);
        *(float4*)(out + (long)Y * 16 + c0)     = make_float4(oY[0], oY[1], oY[2], oY[3]);
        *(float4*)(out + (long)Y * 16 + c0 + 4) = make_float4(oY[4], oY[5], oY[6], oY[7]);
    }
}

extern "C" void kernel_launch(void* const* d_in, const int* in_sizes, int n_in,
                              void* d_out, int out_size, void* d_ws, size_t ws_size,
                              hipStream_t stream)
{
    (void)in_sizes; (void)n_in; (void)out_size; (void)ws_size;
    const float* x     = (const float*)d_in[0];
    const int*   ei    = (const int*)d_in[1];
    const float* w0    = (const float*)d_in[2];
    const float* asrc0 = (const float*)d_in[3];
    const float* adst0 = (const float*)d_in[4];
    const float* b0    = (const float*)d_in[5];
    const float* skip0 = (const float*)d_in[6];
    const float* bn0g  = (const float*)d_in[7];
    const float* bn0b  = (const float*)d_in[8];
    const float* bn0m  = (const float*)d_in[9];
    const float* bn0v  = (const float*)d_in[10];
    const float* w1    = (const float*)d_in[11];
    const float* asrc1 = (const float*)d_in[12];
    const float* adst1 = (const float*)d_in[13];
    const float* b1    = (const float*)d_in[14];
    const float* skip1 = (const float*)d_in[15];
    const float* bn1g  = (const float*)d_in[16];
    const float* bn1b  = (const float*)d_in[17];
    const float* bn1m  = (const float*)d_in[18];
    const float* bn1v  = (const float*)d_in[19];

    // workspace layout
    const long NPAIR = (long)COARSE * CAPR;                         // 1,204,224
    unsigned int* pairs = (unsigned int*)d_ws;                      // NPAIR u32
    unsigned short* wb    = (unsigned short*)(pairs + NPAIR);       // 256*128 bf16
    unsigned short* wb1   = wb + 256 * 128;                         // 32*128
    unsigned short* s0b   = wb1 + 32 * 128;                         // NN*128
    unsigned short* hab   = s0b + (long)NN * 128;                   // NN*128 (bf16 h_act)
    unsigned short* h1b   = hab + (long)NN * 128;                   // NN*16
    unsigned short* srcidx= h1b + (long)NN * 16;                    // NPAIR u16
    unsigned char*  h0f   = (unsigned char*)(srcidx + NPAIR);       // NN*128 fp8
    float* a_src0 = (float*)(h0f + (long)NN * 128);                 // NN*8
    float* a_dst0 = a_src0 + (long)NN * 8;                          // NN*8
    float* s1     = a_dst0 + (long)NN * 8;                          // NN*16
    float* a_src1 = s1 + (long)NN * 16;                             // NN
    float* a_dst1 = a_src1 + NN;                                    // NN
    float2* acb0  = (float2*)(a_dst1 + NN);                         // 128 float2
    float2* acb1  = acb0 + 128;                                     // 16 float2
    int* ccur0  = (int*)(acb1 + 16);                                // COARSE (zeroed)
    int* rowbeg = ccur0 + COARSE;                                   // NN
    int* deg    = rowbeg + NN;                                      // NN

    hipMemsetAsync(ccur0, 0, (size_t)COARSE * 4, stream);

    // dispatch 1: weight cvt + BN consts  ||  partition pass A
    const int PREP_BLKS = CVT_BLKS + (EE + EPB - 1) / EPB;          // 37 + 391
    k_prep<<<PREP_BLKS, 256, 0, stream>>>(
        w0, skip0, w1, skip1,
        b0, bn0g, bn0b, bn0m, bn0v, b1, bn1g, bn1b, bn1m, bn1v,
        (unsigned int*)wb, (unsigned int*)wb1, acb0, acb1,
        ei, ccur0, pairs);

    // dispatch 2: partition pass B  ||  gemm0 (direct fp32 x)
    const int MID_BLKS = COARSE + (NN + 31) / 32;                   // 196 + 1563
    k_mid<<<MID_BLKS, 256, 0, stream>>>(
        pairs, ccur0, srcidx, rowbeg, deg,
        x, wb, asrc0, adst0, h0f, s0b, a_src0, a_dst0);

    // layer 0 aggregation + fused BN/skip/ELU (persistent, 2 nodes/wave)
    k_agg0<<<AGG0_BLKS, 256, 0, stream>>>(rowbeg, deg, srcidx, h0f,
                                          a_src0, a_dst0, s0b, acb0,
                                          hab);
    k_post0<<<(NN / 16 + 3) / 4, 256, 0, stream>>>(hab, wb1, asrc1, adst1,
                                                   h1b, s1, a_src1, a_dst1);
    // layer 1 + epilogue (2 nodes per 8-lane group)
    k_agg1_final<<<(NN / 2 * 8 + 255) / 256, 256, 0, stream>>>(rowbeg, deg, srcidx, h1b,
                                                               a_src1, a_dst1, s1,
                                                               acb1, (float*)d_out);
}